// Round 11
// baseline (257.082 us; speedup 1.0000x reference)
//
#include <hip/hip_runtime.h>
#include <hip/hip_bf16.h>
#include <stdint.h>

typedef __attribute__((ext_vector_type(8))) short s16x8;
typedef __attribute__((ext_vector_type(4))) float f32x4;

#define MFMA16(a, b, c) __builtin_amdgcn_mfma_f32_16x16x32_bf16((a), (b), (c), 0, 0, 0)
#define SBAR() __builtin_amdgcn_s_barrier()

__device__ __forceinline__ void gl_lds16(const void* g, void* l) {
  __builtin_amdgcn_global_load_lds(
      (__attribute__((address_space(1))) void*)(void*)g,
      (__attribute__((address_space(3))) void*)l,
      16, 0, 0);
}

__device__ __forceinline__ unsigned short f2bf(float f) {
  union { float f; uint32_t u; } c; c.f = f;
  return (unsigned short)((c.u + 0x7FFFu + ((c.u >> 16) & 1u)) >> 16);
}

__device__ __forceinline__ f32x4 max4(f32x4 a, f32x4 b) {
  f32x4 c;
  c[0] = fmaxf(a[0], b[0]); c[1] = fmaxf(a[1], b[1]);
  c[2] = fmaxf(a[2], b[2]); c[3] = fmaxf(a[3], b[3]);
  return c;
}

// bijective XCD-aware block swizzle (m204)
__device__ __forceinline__ void xcd_swz(int GX, int GY, int& bx, int& by) {
  int nwg = GX * GY;
  int lid = by * GX + bx;
  int q = nwg >> 3, rm = nwg & 7;
  int xcd = lid & 7, off = lid >> 3;
  int nid = (xcd < rm ? xcd * (q + 1) : rm * (q + 1) + (xcd - rm) * q) + off;
  bx = nid % GX;
  by = nid / GX;
}

// ---------------- merged f32 -> bf16 convert (3 buffers, one launch) ----------------
// na4/nb4/nc4 are FLOAT4 counts (R10 bug: these were divided by 4 twice).
__global__ __launch_bounds__(256) void cvt_all(
    const float* __restrict__ a, unsigned short* __restrict__ oa, int na4,
    const float* __restrict__ b, unsigned short* __restrict__ ob, int nb4,
    const float* __restrict__ c, unsigned short* __restrict__ oc, int nc4) {
  int i = blockIdx.x * 256 + threadIdx.x;
  const float* src; unsigned short* dst; int j;
  if (i < na4) { src = a; dst = oa; j = i; }
  else if (i < na4 + nb4) { src = b; dst = ob; j = i - na4; }
  else if (i < na4 + nb4 + nc4) { src = c; dst = oc; j = i - na4 - nb4; }
  else return;
  float4 v = ((const float4*)src)[j];
  ushort4 o;
  o.x = f2bf(v.x); o.y = f2bf(v.y); o.z = f2bf(v.z); o.w = f2bf(v.w);
  ((ushort4*)dst)[j] = o;
}

// ---------------- conv1d over CLS tokens (f32) ----------------
__global__ __launch_bounds__(256) void conv_cls(
    const float* __restrict__ x,
    const float* __restrict__ wq, const float* __restrict__ bq,
    const float* __restrict__ wk, const float* __restrict__ bk,
    float* __restrict__ tcq, float* __restrict__ tck) {
  __shared__ float g[768][10];  // [ci][t+1], zero-padded both ends
  const int tid = threadIdx.x;
  const int clip = blockIdx.y;
  const int chunk = blockIdx.x;  // 0..23 -> 32 co each
  for (int i = tid; i < 768 * 8; i += 256) {
    int tt = i / 768, ci = i % 768;
    g[ci][tt + 1] = x[(size_t)(clip * 8 + tt) * 151296 + ci];
  }
  for (int i = tid; i < 768; i += 256) { g[i][0] = 0.f; g[i][9] = 0.f; }
  __syncthreads();
  const int co = chunk * 32 + (tid >> 3);
  const int t = tid & 7;
  float aq = 0.f, ak = 0.f;
  const float* wqp = wq + (size_t)co * 2304;
  const float* wkp = wk + (size_t)co * 2304;
  for (int ci = 0; ci < 768; ++ci) {
    float g0 = g[ci][t], g1 = g[ci][t + 1], g2 = g[ci][t + 2];
    aq += g0 * wqp[ci * 3 + 0] + g1 * wqp[ci * 3 + 1] + g2 * wqp[ci * 3 + 2];
    ak += g0 * wkp[ci * 3 + 0] + g1 * wkp[ci * 3 + 1] + g2 * wkp[ci * 3 + 2];
  }
  int b = clip * 8 + t;
  tcq[b * 768 + co] = aq + bq[co];
  tck[b * 768 + co] = ak + bk[co];
}

// ======= fused QKV-GEMM + attention, one block per (b,h), 1024 threads =======
// Phase 1: A(x)-fragments DIRECTLY from global (L2-hot panel, compiler-scheduled
// loads/waits) -> LDS read traffic halves (only W B-frags via LDS). W: 3-buffer
// gl_lds staging, 1 barrier + per-wave counted vmcnt per K-step (in-order vmcnt
// completion => can only over-wait vs compiler-reordered A loads, never under).
// Phase 2 unchanged except setprio around MFMA clusters (T5).
__global__ __launch_bounds__(1024, 4) void qkv_attn(
    const unsigned short* __restrict__ X,    // x_bf 12608x768
    const unsigned short* __restrict__ Wq,   // wqkv_bf 2304x768
    const float* __restrict__ bias,          // 2304
    const float* __restrict__ tcq, const float* __restrict__ tck,  // 64x768 f32
    unsigned short* __restrict__ O) {        // ao_bf 12608x768
  union __align__(16) Smem {
    unsigned short Ws[3][192][64];           // phase-1 W staging: 73.7 KiB
    struct {                                 // phase-2 attention: ~106 KiB
      unsigned short Qs[208][72];
      unsigned short Ks[208][72];
      unsigned short VTs[64][232];
      unsigned short Ps[13][16][40];
    } at;
  };
  __shared__ Smem U;
  __shared__ float tcb[3][64];  // fused bias (+tc)

  const int tid = threadIdx.x;
  const int w = tid >> 6, lane = tid & 63;  // w = 0..15
  int bx = blockIdx.x, by0 = 0;
  xcd_swz(gridDim.x, 1, bx, by0);  // 768 % 8 == 0: same-b heads share XCD
  const int b = bx / 12, h = bx % 12;

  if (tid < 192) {
    int sec = tid >> 6, d = tid & 63;
    float v = bias[sec * 768 + h * 64 + d];
    if (sec == 0) v += tcq[b * 768 + h * 64 + d];
    else if (sec == 1) v += tck[b * 768 + h * 64 + d];
    tcb[sec][d] = v;
  }

  const int wm = w >> 2, wn = w & 3;   // 4M x 4N wave grid for phase 1
  const int r = lane & 15, gq = lane >> 4;
  const int lrow = lane >> 3;
  const int lsw = ((lane & 7) ^ (lrow & 7)) * 8;  // inverse-swizzled 16B slot (elems)
  const int mfn = (wm == 3) ? 4 : 3;   // wm 0..2: rows wm*48..+47; wm 3: 144..207

  f32x4 acc[4][3] = {};
  const size_t xbase = (size_t)b * 197 * 768;
  // per-lane global base for A-frags: row = wm*48 + mf*16 + r, 16B at kk*32+gq*8
  const unsigned short* xrow = X + xbase + (size_t)(wm * 48 + r) * 768 + gq * 8;

  // W staging: 24 chunks of 8 rows x 128B; w<8 -> 2 chunks, w>=8 -> 1
  auto stageW = [&](int buf, int kc) {
#pragma unroll
    for (int j = 0; j < 2; ++j) {
      int c = w + j * 16;
      if (c < 24) {
        int wrow = c * 8 + lrow;
        int sec = wrow >> 6;  // chunks never straddle a 64-row section
        gl_lds16(Wq + (size_t)(sec * 768 + h * 64 + (wrow & 63)) * 768 + kc * 64 + lsw,
                 (char*)&U.Ws[buf][0][0] + c * 1024);
      }
    }
  };
#define WAIT_W()                                                     \
  do {                                                               \
    if (w < 8) asm volatile("s_waitcnt vmcnt(2)" ::: "memory");      \
    else       asm volatile("s_waitcnt vmcnt(1)" ::: "memory");      \
  } while (0)

  stageW(0, 0);
  stageW(1, 1);
  WAIT_W();  // W(0) landed; W(1) in flight
  SBAR();

  for (int kc = 0; kc < 12; ++kc) {
    const int cb = kc % 3;
    if (kc + 2 < 12) stageW((kc + 2) % 3, kc + 2);  // free buffer (barrier'd last iter)
    const char* wb = (const char*)&U.Ws[cb][0][0];
    __builtin_amdgcn_s_setprio(1);
#pragma unroll
    for (int kk = 0; kk < 2; ++kk) {
      s16x8 bfrg[3];
#pragma unroll
      for (int nf = 0; nf < 3; ++nf) {
        int row = wn * 48 + nf * 16 + r;
        bfrg[nf] = *(const s16x8*)(wb + row * 128 + (((kk * 4 + gq) ^ (r & 7)) * 16));
      }
#pragma unroll
      for (int mf = 0; mf < 4; ++mf) {
        if (mf < mfn) {
          // A-frag straight from global (L2-hot); compiler schedules + waits
          s16x8 afr = *(const s16x8*)(xrow + (size_t)mf * 16 * 768 + kc * 64 + kk * 32);
#pragma unroll
          for (int nf = 0; nf < 3; ++nf) acc[mf][nf] = MFMA16(afr, bfrg[nf], acc[mf][nf]);
        }
      }
    }
    __builtin_amdgcn_s_setprio(0);
    if (kc < 10) {       // drain all but own just-issued W batch -> W(kc+1) landed
      WAIT_W();
      SBAR();
    } else if (kc == 10) {
      asm volatile("s_waitcnt vmcnt(0)" ::: "memory");
      SBAR();
    }
  }
  __syncthreads();  // all W reads done before union is repurposed

  // ---- epilogue: Q/K -> LDS row-major, V -> LDS transposed; zero V^T pad cols ----
  for (int i = tid; i < 64 * 35; i += 1024) {
    int d = i / 35, c = 197 + i % 35;
    U.at.VTs[d][c] = 0;
  }
#pragma unroll
  for (int mf = 0; mf < 4; ++mf) {
    if (mf < mfn) {
#pragma unroll
      for (int nf = 0; nf < 3; ++nf) {
        int ncol = wn * 48 + nf * 16 + r;
        int sec = ncol >> 6, d = ncol & 63;
        float bb = tcb[sec][d];
#pragma unroll
        for (int rr = 0; rr < 4; ++rr) {
          int mrow = wm * 48 + mf * 16 + gq * 4 + rr;
          unsigned short bv = f2bf(acc[mf][nf][rr] + bb);
          if (sec == 0)      U.at.Qs[mrow][d] = bv;
          else if (sec == 1) U.at.Ks[mrow][d] = bv;
          else if (mrow < 197) U.at.VTs[d][mrow] = bv;  // keep garbage V out of PV MFMA
        }
      }
    }
  }
  __syncthreads();

  // ---- phase 2: attention; waves 0..12 each own one 16-row q-tile ----
  const int g = gq;
  for (int qt = w; qt < 13; qt += 16) {
    const int q0 = qt * 16;
    int qrow = q0 + r; if (qrow > 196) qrow = 196;
    s16x8 aq0 = *(const s16x8*)&U.at.Qs[qrow][g * 8];
    s16x8 aq1 = *(const s16x8*)&U.at.Qs[qrow][32 + g * 8];

    f32x4 s[13];
    __builtin_amdgcn_s_setprio(1);
#pragma unroll
    for (int j = 0; j < 13; ++j) {
      f32x4 z = {};
      z = MFMA16(aq0, *(const s16x8*)&U.at.Ks[j * 16 + r][g * 8], z);
      z = MFMA16(aq1, *(const s16x8*)&U.at.Ks[j * 16 + r][32 + g * 8], z);
      s[j] = z;
    }
    __builtin_amdgcn_s_setprio(0);
    if (r >= 5) { s[12][0] = -1e30f; s[12][1] = -1e30f; s[12][2] = -1e30f; s[12][3] = -1e30f; }

    f32x4 mx = s[0];
#pragma unroll
    for (int j = 1; j < 13; ++j) mx = max4(mx, s[j]);
#pragma unroll
    for (int off = 1; off < 16; off <<= 1) {
      f32x4 o_;
      o_[0] = __shfl_xor(mx[0], off, 64); o_[1] = __shfl_xor(mx[1], off, 64);
      o_[2] = __shfl_xor(mx[2], off, 64); o_[3] = __shfl_xor(mx[3], off, 64);
      mx = max4(mx, o_);
    }
    const float cexp = 0.125f * 1.44269504088896f;  // scale * log2(e)
    f32x4 sum = {};
#pragma unroll
    for (int j = 0; j < 13; ++j) {
      f32x4 p;
      p[0] = exp2f((s[j][0] - mx[0]) * cexp); p[1] = exp2f((s[j][1] - mx[1]) * cexp);
      p[2] = exp2f((s[j][2] - mx[2]) * cexp); p[3] = exp2f((s[j][3] - mx[3]) * cexp);
      s[j] = p;
      sum += p;
    }
#pragma unroll
    for (int off = 1; off < 16; off <<= 1) {
      sum[0] += __shfl_xor(sum[0], off, 64); sum[1] += __shfl_xor(sum[1], off, 64);
      sum[2] += __shfl_xor(sum[2], off, 64); sum[3] += __shfl_xor(sum[3], off, 64);
    }

    f32x4 o4[4] = {};
    for (int ks = 0; ks < 7; ++ks) {
      int j0 = ks * 2;
#pragma unroll
      for (int jj = 0; jj < 2; ++jj) {
        int jt = j0 + jj;
        int colb = jj * 16 + r;
        if (jt < 13) {
          f32x4 p = s[jt < 13 ? jt : 0];
          U.at.Ps[w][g * 4 + 0][colb] = f2bf(p[0]);
          U.at.Ps[w][g * 4 + 1][colb] = f2bf(p[1]);
          U.at.Ps[w][g * 4 + 2][colb] = f2bf(p[2]);
          U.at.Ps[w][g * 4 + 3][colb] = f2bf(p[3]);
        } else {
          U.at.Ps[w][g * 4 + 0][colb] = 0; U.at.Ps[w][g * 4 + 1][colb] = 0;
          U.at.Ps[w][g * 4 + 2][colb] = 0; U.at.Ps[w][g * 4 + 3][colb] = 0;
        }
      }
      asm volatile("s_waitcnt lgkmcnt(0)" ::: "memory");  // wave-local P transpose RAW
      s16x8 ap = *(const s16x8*)&U.at.Ps[w][r][g * 8];
      __builtin_amdgcn_s_setprio(1);
#pragma unroll
      for (int n = 0; n < 4; ++n)
        o4[n] = MFMA16(ap, *(const s16x8*)&U.at.VTs[n * 16 + r][ks * 32 + g * 8], o4[n]);
      __builtin_amdgcn_s_setprio(0);
    }

    f32x4 rinv;
    rinv[0] = 1.0f / sum[0]; rinv[1] = 1.0f / sum[1];
    rinv[2] = 1.0f / sum[2]; rinv[3] = 1.0f / sum[3];
#pragma unroll
    for (int n = 0; n < 4; ++n) {
#pragma unroll
      for (int rr = 0; rr < 4; ++rr) {
        int qr = q0 + g * 4 + rr;
        if (qr < 197)
          O[((size_t)(b * 197 + qr)) * 768 + h * 64 + n * 16 + r] = f2bf(o4[n][rr] * rinv[rr]);
      }
    }
  }
#undef WAIT_W
}

// ======= projection GEMM: BM=192 BN=128, 512 thr, 80KB LDS, grid 396 = 1 round =======
__global__ __launch_bounds__(512, 4) void proj_gemm(
    const unsigned short* __restrict__ A,   // attn out bf16 12608x768
    const unsigned short* __restrict__ Bw,  // w_proj bf16 768x768
    const float* __restrict__ bias,         // 768
    float* __restrict__ Out) {
  __shared__ __align__(16) unsigned short As[2][192][64];
  __shared__ __align__(16) unsigned short Bs[2][128][64];
  const int tid = threadIdx.x;
  const int w = tid >> 6, lane = tid & 63;
  const int wm = w >> 1, wn = w & 1;   // 4M x 2N wave grid
  const int r = lane & 15, gq = lane >> 4;
  int bx = blockIdx.x, by = blockIdx.y;
  xcd_swz(gridDim.x, gridDim.y, bx, by);
  const int m0 = by * 192, n0 = bx * 128;
  const int lrow = lane >> 3;
  const int lsw = ((lane & 7) ^ (lrow & 7)) * 8;

  f32x4 acc[3][4] = {};

  auto stage = [&](int buf, int kt) {  // 5 gl_lds per wave (3 A + 2 B)
#pragma unroll
    for (int j = 0; j < 3; ++j) {
      int c = w + j * 8;  // A chunks 0..23
      int row = c * 8 + lrow;
      gl_lds16(A + (size_t)(m0 + row) * 768 + kt * 64 + lsw, (char*)&As[buf][0][0] + c * 1024);
    }
#pragma unroll
    for (int j = 0; j < 2; ++j) {
      int c = w + j * 8;  // B chunks 0..15
      int row = c * 8 + lrow;
      gl_lds16(Bw + (size_t)(n0 + row) * 768 + kt * 64 + lsw, (char*)&Bs[buf][0][0] + c * 1024);
    }
  };

  stage(0, 0);
  stage(1, 1);
  asm volatile("s_waitcnt vmcnt(5)" ::: "memory");
  SBAR();

  for (int kt = 0; kt < 12; ++kt) {
    const int cur = kt & 1;
    s16x8 af[2][3], bfr[2][4];
#pragma unroll
    for (int kk = 0; kk < 2; ++kk) {
#pragma unroll
      for (int m = 0; m < 3; ++m) {
        int row = wm * 48 + m * 16 + r;
        af[kk][m] = *(const s16x8*)((const char*)&As[cur][0][0] + row * 128 +
                                    (((kk * 4 + gq) ^ (r & 7)) * 16));
      }
#pragma unroll
      for (int n = 0; n < 4; ++n) {
        int row = wn * 64 + n * 16 + r;
        bfr[kk][n] = *(const s16x8*)((const char*)&Bs[cur][0][0] + row * 128 +
                                     (((kk * 4 + gq) ^ (r & 7)) * 16));
      }
    }
    asm volatile("s_waitcnt lgkmcnt(0)" ::: "memory");
    __builtin_amdgcn_sched_barrier(0);
    SBAR();
    if (kt + 2 < 12) stage(cur, kt + 2);
    __builtin_amdgcn_s_setprio(1);
#pragma unroll
    for (int kk = 0; kk < 2; ++kk)
#pragma unroll
      for (int m = 0; m < 3; ++m)
#pragma unroll
        for (int n = 0; n < 4; ++n) acc[m][n] = MFMA16(af[kk][m], bfr[kk][n], acc[m][n]);
    __builtin_amdgcn_s_setprio(0);
    if (kt < 11) {
      if (kt < 10) asm volatile("s_waitcnt vmcnt(5)" ::: "memory");
      else         asm volatile("s_waitcnt vmcnt(0)" ::: "memory");
      SBAR();
    }
  }

#pragma unroll
  for (int m = 0; m < 3; ++m) {
#pragma unroll
    for (int n = 0; n < 4; ++n) {
#pragma unroll
      for (int rr = 0; rr < 4; ++rr) {
        int M = m0 + wm * 48 + m * 16 + gq * 4 + rr;
        int N = n0 + wn * 64 + n * 16 + r;
        if (M < 12608) Out[(size_t)M * 768 + N] = acc[m][n][rr] + bias[N];
      }
    }
  }
}

extern "C" void kernel_launch(void* const* d_in, const int* in_sizes, int n_in,
                              void* d_out, int out_size, void* d_ws, size_t ws_size,
                              hipStream_t stream) {
  const float* x       = (const float*)d_in[0];
  const float* w_qkv   = (const float*)d_in[1];
  const float* b_qkv   = (const float*)d_in[2];
  const float* w_proj  = (const float*)d_in[3];
  const float* b_proj  = (const float*)d_in[4];
  const float* conv_qw = (const float*)d_in[5];
  const float* conv_qb = (const float*)d_in[6];
  const float* conv_kw = (const float*)d_in[7];
  const float* conv_kb = (const float*)d_in[8];
  float* out = (float*)d_out;

  char* ws = (char*)d_ws;
  size_t off = 0;
  auto alloc = [&](size_t n) {
    char* p = ws + off;
    off = (off + n + 255) & ~(size_t)255;
    return p;
  };
  // order matters: OOB tile reads from x_bf (rows 197..207 of last b) and
  // ao_bf (proj M-tiles past 12608) must land inside the workspace
  unsigned short* x_bf    = (unsigned short*)alloc(12608ull * 768 * 2);
  unsigned short* ao_bf   = (unsigned short*)alloc(12608ull * 768 * 2);
  unsigned short* wqkv_bf = (unsigned short*)alloc(2304ull * 768 * 2);
  unsigned short* wproj_bf= (unsigned short*)alloc(768ull * 768 * 2);
  float* tcq = (float*)alloc(64 * 768 * 4);
  float* tck = (float*)alloc(64 * 768 * 4);
  if (off > ws_size) return;  // workspace too small; fail visibly

  // FLOAT4 counts (R10 bug: these were erroneously divided by 4 again)
  const int na4 = 2420736, nb4 = 442368, nc4 = 147456;
  cvt_all<<<dim3((na4 + nb4 + nc4 + 255) / 256), 256, 0, stream>>>(
      x, x_bf, na4, w_qkv, wqkv_bf, nb4, w_proj, wproj_bf, nc4);
  conv_cls<<<dim3(24, 8), 256, 0, stream>>>(x, conv_qw, conv_qb, conv_kw, conv_kb, tcq, tck);
  qkv_attn<<<dim3(768), 1024, 0, stream>>>(x_bf, wqkv_bf, b_qkv, tcq, tck, ao_bf);
  proj_gemm<<<dim3(6, 66), 512, 0, stream>>>(ao_bf, wproj_bf, b_proj, out);
}

// Round 12
// 187.426 us; speedup vs baseline: 1.3716x; 1.3716x over previous
//
#include <hip/hip_runtime.h>
#include <hip/hip_bf16.h>
#include <stdint.h>

typedef __attribute__((ext_vector_type(8))) short s16x8;
typedef __attribute__((ext_vector_type(4))) float f32x4;

#define MFMA16(a, b, c) __builtin_amdgcn_mfma_f32_16x16x32_bf16((a), (b), (c), 0, 0, 0)
#define SBAR() __builtin_amdgcn_s_barrier()

__device__ __forceinline__ void gl_lds16(const void* g, void* l) {
  __builtin_amdgcn_global_load_lds(
      (__attribute__((address_space(1))) void*)(void*)g,
      (__attribute__((address_space(3))) void*)l,
      16, 0, 0);
}

__device__ __forceinline__ unsigned short f2bf(float f) {
  union { float f; uint32_t u; } c; c.f = f;
  return (unsigned short)((c.u + 0x7FFFu + ((c.u >> 16) & 1u)) >> 16);
}

__device__ __forceinline__ f32x4 max4(f32x4 a, f32x4 b) {
  f32x4 c;
  c[0] = fmaxf(a[0], b[0]); c[1] = fmaxf(a[1], b[1]);
  c[2] = fmaxf(a[2], b[2]); c[3] = fmaxf(a[3], b[3]);
  return c;
}

// bijective XCD-aware block swizzle (m204)
__device__ __forceinline__ void xcd_swz(int GX, int GY, int& bx, int& by) {
  int nwg = GX * GY;
  int lid = by * GX + bx;
  int q = nwg >> 3, rm = nwg & 7;
  int xcd = lid & 7, off = lid >> 3;
  int nid = (xcd < rm ? xcd * (q + 1) : rm * (q + 1) + (xcd - rm) * q) + off;
  bx = nid % GX;
  by = nid / GX;
}

// ---------------- merged f32 -> bf16 convert (3 buffers, one launch) ----------------
// na4/nb4/nc4 are FLOAT4 counts.
__global__ __launch_bounds__(256) void cvt_all(
    const float* __restrict__ a, unsigned short* __restrict__ oa, int na4,
    const float* __restrict__ b, unsigned short* __restrict__ ob, int nb4,
    const float* __restrict__ c, unsigned short* __restrict__ oc, int nc4) {
  int i = blockIdx.x * 256 + threadIdx.x;
  const float* src; unsigned short* dst; int j;
  if (i < na4) { src = a; dst = oa; j = i; }
  else if (i < na4 + nb4) { src = b; dst = ob; j = i - na4; }
  else if (i < na4 + nb4 + nc4) { src = c; dst = oc; j = i - na4 - nb4; }
  else return;
  float4 v = ((const float4*)src)[j];
  ushort4 o;
  o.x = f2bf(v.x); o.y = f2bf(v.y); o.z = f2bf(v.z); o.w = f2bf(v.w);
  ((ushort4*)dst)[j] = o;
}

// ---------------- conv1d over CLS tokens (f32) ----------------
__global__ __launch_bounds__(256) void conv_cls(
    const float* __restrict__ x,
    const float* __restrict__ wq, const float* __restrict__ bq,
    const float* __restrict__ wk, const float* __restrict__ bk,
    float* __restrict__ tcq, float* __restrict__ tck) {
  __shared__ float g[768][10];  // [ci][t+1], zero-padded both ends
  const int tid = threadIdx.x;
  const int clip = blockIdx.y;
  const int chunk = blockIdx.x;  // 0..23 -> 32 co each
  for (int i = tid; i < 768 * 8; i += 256) {
    int tt = i / 768, ci = i % 768;
    g[ci][tt + 1] = x[(size_t)(clip * 8 + tt) * 151296 + ci];
  }
  for (int i = tid; i < 768; i += 256) { g[i][0] = 0.f; g[i][9] = 0.f; }
  __syncthreads();
  const int co = chunk * 32 + (tid >> 3);
  const int t = tid & 7;
  float aq = 0.f, ak = 0.f;
  const float* wqp = wq + (size_t)co * 2304;
  const float* wkp = wk + (size_t)co * 2304;
  for (int ci = 0; ci < 768; ++ci) {
    float g0 = g[ci][t], g1 = g[ci][t + 1], g2 = g[ci][t + 2];
    aq += g0 * wqp[ci * 3 + 0] + g1 * wqp[ci * 3 + 1] + g2 * wqp[ci * 3 + 2];
    ak += g0 * wkp[ci * 3 + 0] + g1 * wkp[ci * 3 + 1] + g2 * wkp[ci * 3 + 2];
  }
  int b = clip * 8 + t;
  tcq[b * 768 + co] = aq + bq[co];
  tck[b * 768 + co] = ak + bk[co];
}

// ======= fused QKV-GEMM + attention, one block per (b,h), 1024 threads =======
// R9 structure (benched 104us): 16 waves = 4 waves/SIMD. Phase 1: 4Mx4N wave
// grid, acc[<=4][3]; Xs+Ws 3-buffer gl_lds staging, per-wave counted vmcnt.
// Phase 2: 13 q-tiles on waves 0..12, + T5 setprio around MFMA clusters.
__global__ __launch_bounds__(1024, 4) void qkv_attn(
    const unsigned short* __restrict__ X,    // x_bf 12608x768
    const unsigned short* __restrict__ Wq,   // wqkv_bf 2304x768
    const float* __restrict__ bias,          // 2304
    const float* __restrict__ tcq, const float* __restrict__ tck,  // 64x768 f32
    unsigned short* __restrict__ O) {        // ao_bf 12608x768
  union __align__(16) Smem {
    struct {  // phase-1 staging: 150 KiB
      unsigned short Xs[3][208][64];
      unsigned short Ws[3][192][64];
    } st;
    struct {  // phase-2 attention: ~104 KiB
      unsigned short Qs[208][72];
      unsigned short Ks[208][72];
      unsigned short VTs[64][232];
      unsigned short Ps[13][16][40];
    } at;
  };
  __shared__ Smem U;
  __shared__ float tcb[3][64];  // fused bias (+tc)

  const int tid = threadIdx.x;
  const int w = tid >> 6, lane = tid & 63;  // w = 0..15
  int bx = blockIdx.x, by0 = 0;
  xcd_swz(gridDim.x, 1, bx, by0);  // 768 % 8 == 0: same-b heads share XCD
  const int b = bx / 12, h = bx % 12;

  if (tid < 192) {
    int sec = tid >> 6, d = tid & 63;
    float v = bias[sec * 768 + h * 64 + d];
    if (sec == 0) v += tcq[b * 768 + h * 64 + d];
    else if (sec == 1) v += tck[b * 768 + h * 64 + d];
    tcb[sec][d] = v;
  }

  const int wm = w >> 2, wn = w & 3;   // 4M x 4N wave grid for phase 1
  const int r = lane & 15, gq = lane >> 4;
  const int lrow = lane >> 3;
  const int lsw = ((lane & 7) ^ (lrow & 7)) * 8;  // inverse-swizzled 16B slot (elems)
  const int mfn = (wm == 3) ? 4 : 3;   // wm 0..2: rows wm*48..+47; wm 3: 144..207

  f32x4 acc[4][3] = {};
  const size_t xbase = (size_t)b * 197 * 768;

  // per-wave gl_lds per stage(): w<8 -> 2X+2W=4; w=8,9 -> 2X+1W=3; w>=10 -> 1X+1W=2
  auto stage = [&](int buf, int kc) {
#pragma unroll
    for (int j = 0; j < 2; ++j) {
      int c = w + j * 16;  // X chunks 0..25
      if (c < 26) {
        int row = c * 8 + lrow;
        gl_lds16(X + xbase + (size_t)row * 768 + kc * 64 + lsw,
                 (char*)&U.st.Xs[buf][0][0] + c * 1024);
      }
    }
#pragma unroll
    for (int j = 0; j < 2; ++j) {
      int c = w + j * 16;  // W chunks 0..23 (never straddle a 64-row section)
      if (c < 24) {
        int wrow = c * 8 + lrow;
        int sec = wrow >> 6;
        gl_lds16(Wq + (size_t)(sec * 768 + h * 64 + (wrow & 63)) * 768 + kc * 64 + lsw,
                 (char*)&U.st.Ws[buf][0][0] + c * 1024);
      }
    }
  };

#define WAIT_OWN()                                                 \
  do {                                                             \
    if (w < 8)       asm volatile("s_waitcnt vmcnt(4)" ::: "memory"); \
    else if (w < 10) asm volatile("s_waitcnt vmcnt(3)" ::: "memory"); \
    else             asm volatile("s_waitcnt vmcnt(2)" ::: "memory"); \
  } while (0)

  stage(0, 0);
  stage(1, 1);
  WAIT_OWN();  // tile 0 landed; tile 1 in flight
  SBAR();

  for (int kc = 0; kc < 12; ++kc) {
    const int cb = kc % 3;
    if (kc + 2 < 12) stage((kc + 2) % 3, kc + 2);  // into free buffer
    const char* xb = (const char*)&U.st.Xs[cb][0][0];
    const char* wb = (const char*)&U.st.Ws[cb][0][0];
    __builtin_amdgcn_s_setprio(1);
#pragma unroll
    for (int kk = 0; kk < 2; ++kk) {
      s16x8 bfrg[3];
#pragma unroll
      for (int nf = 0; nf < 3; ++nf) {
        int row = wn * 48 + nf * 16 + r;
        bfrg[nf] = *(const s16x8*)(wb + row * 128 + (((kk * 4 + gq) ^ (r & 7)) * 16));
      }
#pragma unroll
      for (int mf = 0; mf < 4; ++mf) {
        if (mf < mfn) {
          int row = wm * 48 + mf * 16 + r;
          s16x8 afr = *(const s16x8*)(xb + row * 128 + (((kk * 4 + gq) ^ (r & 7)) * 16));
#pragma unroll
          for (int nf = 0; nf < 3; ++nf) acc[mf][nf] = MFMA16(afr, bfrg[nf], acc[mf][nf]);
        }
      }
    }
    __builtin_amdgcn_s_setprio(0);
    if (kc < 10) {  // own just-issued loads remain; tile kc+1 guaranteed landed
      WAIT_OWN();
      SBAR();
    } else if (kc == 10) {
      asm volatile("s_waitcnt vmcnt(0)" ::: "memory");
      SBAR();
    }
  }
  __syncthreads();  // all waves done reading tile 11 before union is repurposed

  // ---- epilogue: Q/K -> LDS row-major, V -> LDS transposed; zero V^T pad cols ----
  for (int i = tid; i < 64 * 35; i += 1024) {
    int d = i / 35, c = 197 + i % 35;
    U.at.VTs[d][c] = 0;
  }
#pragma unroll
  for (int mf = 0; mf < 4; ++mf) {
    if (mf < mfn) {
#pragma unroll
      for (int nf = 0; nf < 3; ++nf) {
        int ncol = wn * 48 + nf * 16 + r;
        int sec = ncol >> 6, d = ncol & 63;
        float bb = tcb[sec][d];
#pragma unroll
        for (int rr = 0; rr < 4; ++rr) {
          int mrow = wm * 48 + mf * 16 + gq * 4 + rr;
          unsigned short bv = f2bf(acc[mf][nf][rr] + bb);
          if (sec == 0)      U.at.Qs[mrow][d] = bv;
          else if (sec == 1) U.at.Ks[mrow][d] = bv;
          else if (mrow < 197) U.at.VTs[d][mrow] = bv;  // keep garbage V out of PV MFMA
        }
      }
    }
  }
  __syncthreads();

  // ---- phase 2: attention; waves 0..12 each own one 16-row q-tile ----
  const int g = gq;
  for (int qt = w; qt < 13; qt += 16) {
    const int q0 = qt * 16;
    int qrow = q0 + r; if (qrow > 196) qrow = 196;
    s16x8 aq0 = *(const s16x8*)&U.at.Qs[qrow][g * 8];
    s16x8 aq1 = *(const s16x8*)&U.at.Qs[qrow][32 + g * 8];

    f32x4 s[13];
    __builtin_amdgcn_s_setprio(1);
#pragma unroll
    for (int j = 0; j < 13; ++j) {
      f32x4 z = {};
      z = MFMA16(aq0, *(const s16x8*)&U.at.Ks[j * 16 + r][g * 8], z);
      z = MFMA16(aq1, *(const s16x8*)&U.at.Ks[j * 16 + r][32 + g * 8], z);
      s[j] = z;
    }
    __builtin_amdgcn_s_setprio(0);
    if (r >= 5) { s[12][0] = -1e30f; s[12][1] = -1e30f; s[12][2] = -1e30f; s[12][3] = -1e30f; }

    f32x4 mx = s[0];
#pragma unroll
    for (int j = 1; j < 13; ++j) mx = max4(mx, s[j]);
#pragma unroll
    for (int off = 1; off < 16; off <<= 1) {
      f32x4 o_;
      o_[0] = __shfl_xor(mx[0], off, 64); o_[1] = __shfl_xor(mx[1], off, 64);
      o_[2] = __shfl_xor(mx[2], off, 64); o_[3] = __shfl_xor(mx[3], off, 64);
      mx = max4(mx, o_);
    }
    const float cexp = 0.125f * 1.44269504088896f;  // scale * log2(e)
    f32x4 sum = {};
#pragma unroll
    for (int j = 0; j < 13; ++j) {
      f32x4 p;
      p[0] = exp2f((s[j][0] - mx[0]) * cexp); p[1] = exp2f((s[j][1] - mx[1]) * cexp);
      p[2] = exp2f((s[j][2] - mx[2]) * cexp); p[3] = exp2f((s[j][3] - mx[3]) * cexp);
      s[j] = p;
      sum += p;
    }
#pragma unroll
    for (int off = 1; off < 16; off <<= 1) {
      sum[0] += __shfl_xor(sum[0], off, 64); sum[1] += __shfl_xor(sum[1], off, 64);
      sum[2] += __shfl_xor(sum[2], off, 64); sum[3] += __shfl_xor(sum[3], off, 64);
    }

    f32x4 o4[4] = {};
    for (int ks = 0; ks < 7; ++ks) {
      int j0 = ks * 2;
#pragma unroll
      for (int jj = 0; jj < 2; ++jj) {
        int jt = j0 + jj;
        int colb = jj * 16 + r;
        if (jt < 13) {
          f32x4 p = s[jt < 13 ? jt : 0];
          U.at.Ps[w][g * 4 + 0][colb] = f2bf(p[0]);
          U.at.Ps[w][g * 4 + 1][colb] = f2bf(p[1]);
          U.at.Ps[w][g * 4 + 2][colb] = f2bf(p[2]);
          U.at.Ps[w][g * 4 + 3][colb] = f2bf(p[3]);
        } else {
          U.at.Ps[w][g * 4 + 0][colb] = 0; U.at.Ps[w][g * 4 + 1][colb] = 0;
          U.at.Ps[w][g * 4 + 2][colb] = 0; U.at.Ps[w][g * 4 + 3][colb] = 0;
        }
      }
      asm volatile("s_waitcnt lgkmcnt(0)" ::: "memory");  // wave-local P transpose RAW
      s16x8 ap = *(const s16x8*)&U.at.Ps[w][r][g * 8];
      __builtin_amdgcn_s_setprio(1);
#pragma unroll
      for (int n = 0; n < 4; ++n)
        o4[n] = MFMA16(ap, *(const s16x8*)&U.at.VTs[n * 16 + r][ks * 32 + g * 8], o4[n]);
      __builtin_amdgcn_s_setprio(0);
    }

    f32x4 rinv;
    rinv[0] = 1.0f / sum[0]; rinv[1] = 1.0f / sum[1];
    rinv[2] = 1.0f / sum[2]; rinv[3] = 1.0f / sum[3];
#pragma unroll
    for (int n = 0; n < 4; ++n) {
#pragma unroll
      for (int rr = 0; rr < 4; ++rr) {
        int qr = q0 + g * 4 + rr;
        if (qr < 197)
          O[((size_t)(b * 197 + qr)) * 768 + h * 64 + n * 16 + r] = f2bf(o4[n][rr] * rinv[rr]);
      }
    }
  }
#undef WAIT_OWN
}

// ======= projection GEMM: BM=192 BN=128, 512 thr, 80KB LDS, grid 396 = 1 round =======
__global__ __launch_bounds__(512, 4) void proj_gemm(
    const unsigned short* __restrict__ A,   // attn out bf16 12608x768
    const unsigned short* __restrict__ Bw,  // w_proj bf16 768x768
    const float* __restrict__ bias,         // 768
    float* __restrict__ Out) {
  __shared__ __align__(16) unsigned short As[2][192][64];
  __shared__ __align__(16) unsigned short Bs[2][128][64];
  const int tid = threadIdx.x;
  const int w = tid >> 6, lane = tid & 63;
  const int wm = w >> 1, wn = w & 1;   // 4M x 2N wave grid
  const int r = lane & 15, gq = lane >> 4;
  int bx = blockIdx.x, by = blockIdx.y;
  xcd_swz(gridDim.x, gridDim.y, bx, by);
  const int m0 = by * 192, n0 = bx * 128;
  const int lrow = lane >> 3;
  const int lsw = ((lane & 7) ^ (lrow & 7)) * 8;

  f32x4 acc[3][4] = {};

  auto stage = [&](int buf, int kt) {  // 5 gl_lds per wave (3 A + 2 B)
#pragma unroll
    for (int j = 0; j < 3; ++j) {
      int c = w + j * 8;  // A chunks 0..23
      int row = c * 8 + lrow;
      gl_lds16(A + (size_t)(m0 + row) * 768 + kt * 64 + lsw, (char*)&As[buf][0][0] + c * 1024);
    }
#pragma unroll
    for (int j = 0; j < 2; ++j) {
      int c = w + j * 8;  // B chunks 0..15
      int row = c * 8 + lrow;
      gl_lds16(Bw + (size_t)(n0 + row) * 768 + kt * 64 + lsw, (char*)&Bs[buf][0][0] + c * 1024);
    }
  };

  stage(0, 0);
  stage(1, 1);
  asm volatile("s_waitcnt vmcnt(5)" ::: "memory");
  SBAR();

  for (int kt = 0; kt < 12; ++kt) {
    const int cur = kt & 1;
    s16x8 af[2][3], bfr[2][4];
#pragma unroll
    for (int kk = 0; kk < 2; ++kk) {
#pragma unroll
      for (int m = 0; m < 3; ++m) {
        int row = wm * 48 + m * 16 + r;
        af[kk][m] = *(const s16x8*)((const char*)&As[cur][0][0] + row * 128 +
                                    (((kk * 4 + gq) ^ (r & 7)) * 16));
      }
#pragma unroll
      for (int n = 0; n < 4; ++n) {
        int row = wn * 64 + n * 16 + r;
        bfr[kk][n] = *(const s16x8*)((const char*)&Bs[cur][0][0] + row * 128 +
                                     (((kk * 4 + gq) ^ (r & 7)) * 16));
      }
    }
    asm volatile("s_waitcnt lgkmcnt(0)" ::: "memory");
    __builtin_amdgcn_sched_barrier(0);
    SBAR();
    if (kt + 2 < 12) stage(cur, kt + 2);
    __builtin_amdgcn_s_setprio(1);
#pragma unroll
    for (int kk = 0; kk < 2; ++kk)
#pragma unroll
      for (int m = 0; m < 3; ++m)
#pragma unroll
        for (int n = 0; n < 4; ++n) acc[m][n] = MFMA16(af[kk][m], bfr[kk][n], acc[m][n]);
    __builtin_amdgcn_s_setprio(0);
    if (kt < 11) {
      if (kt < 10) asm volatile("s_waitcnt vmcnt(5)" ::: "memory");
      else         asm volatile("s_waitcnt vmcnt(0)" ::: "memory");
      SBAR();
    }
  }

#pragma unroll
  for (int m = 0; m < 3; ++m) {
#pragma unroll
    for (int n = 0; n < 4; ++n) {
#pragma unroll
      for (int rr = 0; rr < 4; ++rr) {
        int M = m0 + wm * 48 + m * 16 + gq * 4 + rr;
        int N = n0 + wn * 64 + n * 16 + r;
        if (M < 12608) Out[(size_t)M * 768 + N] = acc[m][n][rr] + bias[N];
      }
    }
  }
}

extern "C" void kernel_launch(void* const* d_in, const int* in_sizes, int n_in,
                              void* d_out, int out_size, void* d_ws, size_t ws_size,
                              hipStream_t stream) {
  const float* x       = (const float*)d_in[0];
  const float* w_qkv   = (const float*)d_in[1];
  const float* b_qkv   = (const float*)d_in[2];
  const float* w_proj  = (const float*)d_in[3];
  const float* b_proj  = (const float*)d_in[4];
  const float* conv_qw = (const float*)d_in[5];
  const float* conv_qb = (const float*)d_in[6];
  const float* conv_kw = (const float*)d_in[7];
  const float* conv_kb = (const float*)d_in[8];
  float* out = (float*)d_out;

  char* ws = (char*)d_ws;
  size_t off = 0;
  auto alloc = [&](size_t n) {
    char* p = ws + off;
    off = (off + n + 255) & ~(size_t)255;
    return p;
  };
  // order matters: OOB tile reads from x_bf (rows 197..207 of last b) and
  // ao_bf (proj M-tiles past 12608) must land inside the workspace
  unsigned short* x_bf    = (unsigned short*)alloc(12608ull * 768 * 2);
  unsigned short* ao_bf   = (unsigned short*)alloc(12608ull * 768 * 2);
  unsigned short* wqkv_bf = (unsigned short*)alloc(2304ull * 768 * 2);
  unsigned short* wproj_bf= (unsigned short*)alloc(768ull * 768 * 2);
  float* tcq = (float*)alloc(64 * 768 * 4);
  float* tck = (float*)alloc(64 * 768 * 4);
  if (off > ws_size) return;  // workspace too small; fail visibly

  // FLOAT4 counts
  const int na4 = 2420736, nb4 = 442368, nc4 = 147456;
  cvt_all<<<dim3((na4 + nb4 + nc4 + 255) / 256), 256, 0, stream>>>(
      x, x_bf, na4, w_qkv, wqkv_bf, nb4, w_proj, wproj_bf, nc4);
  conv_cls<<<dim3(24, 8), 256, 0, stream>>>(x, conv_qw, conv_qb, conv_kw, conv_kb, tcq, tck);
  qkv_attn<<<dim3(768), 1024, 0, stream>>>(x_bf, wqkv_bf, b_qkv, tcq, tck, ao_bf);
  proj_gemm<<<dim3(6, 66), 512, 0, stream>>>(ao_bf, wproj_bf, b_proj, out);
}